// Round 6
// baseline (1773.874 us; speedup 1.0000x reference)
//
#include <hip/hip_runtime.h>

#define HH 20
#define TSTEPS 256
#define FF 64
#define EPW 32             // batch elements per wave (1 wave per block)
#define NB 2               // n-blocks of 16 elements
#define ROWLEN 72          // f16 per LDS B-row; 144 B stride (16B-aligned)
#define LOG2E 1.44269504088896f
// B-row layout (f16 idx): [0..23] h1, 6-stride (lane q writes 6q..6q+4, 6q+5 pad)
//   [24]=x, [25]=1.0 (bias carrier, written once), [26..49] h2 (6-stride), [50..71] zero

typedef __attribute__((ext_vector_type(8))) _Float16 f16x8;
typedef __attribute__((ext_vector_type(2))) _Float16 f16x2;
typedef __attribute__((ext_vector_type(4))) float    f32x4;
typedef __attribute__((ext_vector_type(2))) float    f32x2;

__device__ __forceinline__ f16x2 pkrtz(float a, float b) {
    return __builtin_bit_cast(f16x2, __builtin_amdgcn_cvt_pkrtz(a, b));
}

__device__ __forceinline__ f32x4 mfma16(f16x8 a, f16x8 b, f32x4 c) {
    return __builtin_amdgcn_mfma_f32_16x16x32_f16(a, b, c, 0, 0, 0);
}
__device__ __forceinline__ float rcpf(float x) { return __builtin_amdgcn_rcpf(x); }
__device__ __forceinline__ float exp2t(float x) {          // trans-pipe 2^x
#if __has_builtin(__builtin_amdgcn_exp2f)
    return __builtin_amdgcn_exp2f(x);
#else
    return __expf(x * 0.6931471805599453f);
#endif
}
// VALU-only 2^x: rndne + deg-4 Taylor on [-0.5,0.5] + native v_ldexp_f32.
// rel err <= ~4e-5 (far below f16 weight quantization).
// 8 full-rate ops = 16 VALU cyc, vs 16 trans-pipe cyc for v_exp_f32.
__device__ __forceinline__ float exp2v(float x) {
    float n = __builtin_rintf(x);                  // v_rndne_f32
    float f = x - n;
    float p = fmaf(f, 0.00961813f, 0.05550411f);   // ln2^4/24, ln2^3/6
    p = fmaf(f, p, 0.24022651f);                   // ln2^2/2
    p = fmaf(f, p, 0.69314718f);                   // ln2
    p = fmaf(f, p, 1.0f);
    return __builtin_ldexpf(p, (int)n);            // v_ldexp_f32
}

// Gate quads arrive pre-scaled: si=-log2e*zi, sf=-log2e*zf, sg=2log2e*zg, so=-log2e*zo.
// 7-trans form split across pipes: {ei,ef,eo} on VALU (exp2v), {eg,ec}+rcps on trans.
// P=(1+ei)(1+eg), Q=(1+ef); c' = (c*P + (eg-1)*Q) * rcp(P*Q)
// h = (ec-1) * rcp((1+eo)(1+ec)),  ec = 2^min(2*log2e*c', 100)
__device__ __forceinline__ f32x2 act_pair(f32x4 za, f32x4 zb, f32x2& c) {
    f32x2 ei; ei.x = exp2v(za.x); ei.y = exp2v(zb.x);      // VALU
    f32x2 ef; ef.x = exp2v(za.y); ef.y = exp2v(zb.y);      // VALU
    f32x2 eg; eg.x = exp2t(za.z); eg.y = exp2t(zb.z);      // trans
    f32x2 eo; eo.x = exp2v(za.w); eo.y = exp2v(zb.w);      // VALU
    const f32x2 one = {1.0f, 1.0f};
    f32x2 P = (one + ei) * (one + eg);
    f32x2 Q = one + ef;
    f32x2 num = c * P + (eg - one) * Q;
    f32x2 den = P * Q;
    f32x2 r; r.x = rcpf(den.x); r.y = rcpf(den.y);         // trans
    c = num * r;
    f32x2 sc = c * (2.0f * LOG2E);
    sc.x = fminf(sc.x, 100.0f); sc.y = fminf(sc.y, 100.0f);   // inf*0 NaN guard
    f32x2 ec; ec.x = exp2t(sc.x); ec.y = exp2t(sc.y);      // trans
    f32x2 den2 = (one + eo) * (one + ec);
    f32x2 r2; r2.x = rcpf(den2.x); r2.y = rcpf(den2.y);    // trans
    return (ec - one) * r2;
}
__device__ __forceinline__ float act_one(f32x4 za, float& c) {
    float ei = exp2v(za.x), ef = exp2v(za.y);              // VALU
    float eg = exp2t(za.z), eo = exp2v(za.w);              // trans / VALU
    float P = (1.0f + ei) * (1.0f + eg);
    float Q = 1.0f + ef;
    float num = fmaf(c, P, (eg - 1.0f) * Q);
    c = num * rcpf(P * Q);
    float sc = fminf(c * (2.0f * LOG2E), 100.0f);
    float ec = exp2t(sc);
    float r2 = rcpf((1.0f + eo) * (1.0f + ec));
    return (ec - 1.0f) * r2;
}

// ---------------------------------------------------------------------------
// Packed augmented weights, f16, PRE-SCALED by the exp2 gate factors.
// Matrix row r (0..79): m=r>>4, q=(r>>2)&3, g=r&3 -> unit u=5q+m, gate g
// (orig row ro = g*20+u). Column k follows the B-row layout above.
//   W1c [80][32] at ws[0..2559]; W2c [80][64] at ws[2560..7679].
// ---------------------------------------------------------------------------
__global__ void prep_weights(
    const float* __restrict__ Wih1, const float* __restrict__ Whh1,
    const float* __restrict__ bih1, const float* __restrict__ bhh1,
    const float* __restrict__ Wih2, const float* __restrict__ Whh2,
    const float* __restrict__ bih2, const float* __restrict__ bhh2,
    _Float16* __restrict__ ws)
{
    const int t0 = blockIdx.x * blockDim.x + threadIdx.x;
    const int stride = blockDim.x * gridDim.x;
    for (int idx = t0; idx < 80 * 32; idx += stride) {
        int r = idx >> 5, k = idx & 31;
        int m = r >> 4, q = (r >> 2) & 3, g = r & 3;
        int u = 5 * q + m, ro = g * HH + u;
        float s = (g == 2) ? 2.0f * LOG2E : -LOG2E;
        float v = 0.0f;
        if (k < 24)       { int qc = k / 6, wc = k % 6; if (wc < 5) v = Whh1[ro * HH + 5 * qc + wc]; }
        else if (k == 24)   v = Wih1[ro];
        else if (k == 25)   v = bih1[ro] + bhh1[ro];
        ws[idx] = (_Float16)(s * v);
    }
    for (int idx = t0; idx < 80 * 64; idx += stride) {
        int r = idx >> 6, k = idx & 63;
        int m = r >> 4, q = (r >> 2) & 3, g = r & 3;
        int u = 5 * q + m, ro = g * HH + u;
        float s = (g == 2) ? 2.0f * LOG2E : -LOG2E;
        float v = 0.0f;
        if (k < 24)       { int qc = k / 6, wc = k % 6; if (wc < 5) v = Wih2[ro * HH + 5 * qc + wc]; }
        else if (k == 25)   v = bih2[ro] + bhh2[ro];
        else if (k >= 26 && k < 50) {
            int cH = k - 26, qc = cH / 6, wc = cH % 6;
            if (wc < 5) v = Whh2[ro * HH + 5 * qc + wc];
        }
        ws[2560 + idx] = (_Float16)(s * v);
    }
}

// ---------------------------------------------------------------------------
// One wave per block, 32 elements per wave (4 waves/SIMD across the grid),
// weights stationary in VGPRs, c in VGPRs. Lane (q=lane>>4, cc=lane&15):
// owns units {5q..5q+4} for the two 16-element n-blocks.
// ---------------------------------------------------------------------------
__global__ __launch_bounds__(64, 4) void lstm_mfma(
    const float* __restrict__ diag,
    const _Float16* __restrict__ wpk,
    const float* __restrict__ W1, const float* __restrict__ b1,
    const float* __restrict__ W2, const float* __restrict__ b2,
    float* __restrict__ out, int Btot)
{
    __shared__ _Float16 s_B[EPW * ROWLEN];     // 4608 B

    const int lane = threadIdx.x;              // 0..63
    const int q  = lane >> 4;
    const int cc = lane & 15;
    const int e  = blockIdx.x * EPW + (lane & (EPW - 1));
    const int esafe = (e < Btot) ? e : (Btot - 1);

    // zero B-rows (one row per lane<32) and set the 1.0 bias carrier ONCE
    if (lane < EPW) {
        uint4 zz = {0u, 0u, 0u, 0u};
        #pragma unroll
        for (int j = 0; j < 9; ++j)
            *(uint4*)((char*)s_B + lane * 144 + j * 16) = zz;
        s_B[lane * ROWLEN + 25] = (_Float16)1.0f;
    }

    // stationary A-fragments: lane supplies A[row=16m+cc][k=8q..8q+7]
    f16x8 A1[5], A2a[5], A2b[5];
    {
        const _Float16* W2c = wpk + 2560;
        const int kb = q * 8;
        #pragma unroll
        for (int m = 0; m < 5; ++m) {
            const int r = 16 * m + cc;
            A1[m]  = *(const f16x8*)(wpk + r * 32 + kb);
            A2a[m] = *(const f16x8*)(W2c + r * 64 + kb);
            A2b[m] = *(const f16x8*)(W2c + r * 64 + 32 + kb);
        }
    }

    // cell state: per n-block, 2 packed pairs + 1 scalar per layer
    f32x2 c1p[NB][2], c2p[NB][2];
    float c1s[NB], c2s[NB];
    #pragma unroll
    for (int n = 0; n < NB; ++n) {
        c1p[n][0] = (f32x2){0.0f, 0.0f}; c1p[n][1] = (f32x2){0.0f, 0.0f};
        c2p[n][0] = (f32x2){0.0f, 0.0f}; c2p[n][1] = (f32x2){0.0f, 0.0f};
        c1s[n] = 0.0f; c2s[n] = 0.0f;
    }

    const float* __restrict__ xr = diag + (long long)esafe * TSTEPS;
    float x = xr[0];
    const f32x4 zz4 = {0.0f, 0.0f, 0.0f, 0.0f};

    #pragma unroll 1
    for (int t = 0; t < TSTEPS; ++t) {
        float xn = xr[(t + 1) & (TSTEPS - 1)];   // prefetch (wraps; unused at end)

        // publish x(t) at k=24 of own row (bias carrier already set)
        if (lane < EPW)
            s_B[lane * ROWLEN + 24] = (_Float16)x;

        // ================= layer 1 =================
        #pragma unroll
        for (int n = 0; n < NB; ++n) {
            const _Float16* rowp = s_B + (n * 16 + cc) * ROWLEN;
            f16x8 bf = *(const f16x8*)(rowp + 8 * q);
            f32x4 z0 = mfma16(A1[0], bf, zz4);
            f32x4 z1 = mfma16(A1[1], bf, zz4);
            f32x4 z2 = mfma16(A1[2], bf, zz4);
            f32x4 z3 = mfma16(A1[3], bf, zz4);
            f32x4 z4 = mfma16(A1[4], bf, zz4);
            _Float16* wp = s_B + (n * 16 + cc) * ROWLEN + 6 * q;
            f32x2 h01 = act_pair(z0, z1, c1p[n][0]);
            *(f16x2*)(wp) = pkrtz(h01.x, h01.y);             // 1 instr pack
            f32x2 h23 = act_pair(z2, z3, c1p[n][1]);
            *(f16x2*)(wp + 2) = pkrtz(h23.x, h23.y);
            float h4 = act_one(z4, c1s[n]);
            wp[4] = (_Float16)h4;
        }

        // ================= layer 2 =================
        #pragma unroll
        for (int n = 0; n < NB; ++n) {
            const _Float16* rowp = s_B + (n * 16 + cc) * ROWLEN;
            f16x8 b0  = *(const f16x8*)(rowp + 8 * q);        // k 0..31
            f16x8 b1f = *(const f16x8*)(rowp + 32 + 8 * q);   // k 32..63
            f32x4 z0 = mfma16(A2b[0], b1f, mfma16(A2a[0], b0, zz4));
            f32x4 z1 = mfma16(A2b[1], b1f, mfma16(A2a[1], b0, zz4));
            f32x4 z2 = mfma16(A2b[2], b1f, mfma16(A2a[2], b0, zz4));
            f32x4 z3 = mfma16(A2b[3], b1f, mfma16(A2a[3], b0, zz4));
            f32x4 z4 = mfma16(A2b[4], b1f, mfma16(A2a[4], b0, zz4));
            _Float16* wp = s_B + (n * 16 + cc) * ROWLEN + 26 + 6 * q;
            f32x2 h01 = act_pair(z0, z1, c2p[n][0]);
            *(f16x2*)(wp) = pkrtz(h01.x, h01.y);
            f32x2 h23 = act_pair(z2, z3, c2p[n][1]);
            *(f16x2*)(wp + 2) = pkrtz(h23.x, h23.y);
            float h4 = act_one(z4, c2s[n]);
            wp[4] = (_Float16)h4;
        }

        x = xn;
    }

    // ---- head: relu(relu(h2 @ W1^T + b1) @ W2^T + b2), fp32, lanes 0..31 ----
    if (lane < EPW && e < Btot) {
        const _Float16* rowp = s_B + lane * ROWLEN + 26;
        float hv[HH];
        #pragma unroll
        for (int qq = 0; qq < 4; ++qq)
            #pragma unroll
            for (int ww = 0; ww < 5; ++ww)
                hv[5 * qq + ww] = (float)rowp[6 * qq + ww];   // un-permute 6-stride

        float y2 = b2[0];
        #pragma unroll 1
        for (int jj = 0; jj < FF; ++jj) {
            float a = b1[jj];
            const float* __restrict__ wj = W1 + jj * HH;
            #pragma unroll
            for (int k = 0; k < HH; ++k)
                a = fmaf(hv[k], wj[k], a);
            a = fmaxf(a, 0.0f);
            y2 = fmaf(a, W2[jj], y2);
        }
        out[e] = fmaxf(y2, 0.0f);
    }
}

extern "C" void kernel_launch(void* const* d_in, const int* in_sizes, int n_in,
                              void* d_out, int out_size, void* d_ws, size_t ws_size,
                              hipStream_t stream)
{
    (void)n_in; (void)ws_size; (void)out_size;
    const float* diag = (const float*)d_in[0];
    const float* Wih1 = (const float*)d_in[1];
    const float* Whh1 = (const float*)d_in[2];
    const float* bih1 = (const float*)d_in[3];
    const float* bhh1 = (const float*)d_in[4];
    const float* Wih2 = (const float*)d_in[5];
    const float* Whh2 = (const float*)d_in[6];
    const float* bih2 = (const float*)d_in[7];
    const float* bhh2 = (const float*)d_in[8];
    const float* W1   = (const float*)d_in[9];
    const float* b1   = (const float*)d_in[10];
    const float* W2   = (const float*)d_in[11];
    const float* b2   = (const float*)d_in[12];

    const int Btot = in_sizes[0] / TSTEPS;   // 131072
    _Float16* wpk = (_Float16*)d_ws;

    prep_weights<<<8, 256, 0, stream>>>(Wih1, Whh1, bih1, bhh1,
                                        Wih2, Whh2, bih2, bhh2, wpk);

    lstm_mfma<<<(Btot + EPW - 1) / EPW, 64, 0, stream>>>(
        diag, wpk, W1, b1, W2, b2, (float*)d_out, Btot);
}

// Round 7
// 1261.293 us; speedup vs baseline: 1.4064x; 1.4064x over previous
//
#include <hip/hip_runtime.h>

#define HH 20
#define TSTEPS 256
#define FF 64
#define EPW 16             // batch elements per wave
#define WAVES 4            // waves per block
#define ELPB (EPW * WAVES) // 64 elements per block
#define ROWLEN 72          // f16 per LDS B-row; 144 B stride (16B-aligned)
#define LOG2E 1.44269504088896f
// B-row layout (f16 idx): [0..23] h1, 6-stride (lane q writes 6q..6q+4, 6q+5 pad)
//   [24]=x, [25]=1.0 (bias carrier, written once), [26..49] h2 (6-stride), [50..71] zero

typedef __attribute__((ext_vector_type(8))) _Float16 f16x8;
typedef __attribute__((ext_vector_type(2))) _Float16 f16x2;
typedef __attribute__((ext_vector_type(4))) float    f32x4;
typedef __attribute__((ext_vector_type(2))) float    f32x2;

__device__ __forceinline__ f16x2 pkrtz(float a, float b) {
    return __builtin_bit_cast(f16x2, __builtin_amdgcn_cvt_pkrtz(a, b));
}
__device__ __forceinline__ f32x4 mfma16(f16x8 a, f16x8 b, f32x4 c) {
    return __builtin_amdgcn_mfma_f32_16x16x32_f16(a, b, c, 0, 0, 0);
}
__device__ __forceinline__ float rcpf(float x) { return __builtin_amdgcn_rcpf(x); }
__device__ __forceinline__ float exp2t(float x) {          // v_exp_f32 (2^x native)
#if __has_builtin(__builtin_amdgcn_exp2f)
    return __builtin_amdgcn_exp2f(x);
#else
    return __expf(x * 0.6931471805599453f);
#endif
}

// Gate quads arrive pre-scaled: si=-log2e*zi, sf=-log2e*zf, sg=2log2e*zg, so=-log2e*zo.
// 7-trans form (R4, measured-best): P=(1+ei)(1+eg), Q=(1+ef);
//   c' = (c*P + (eg-1)*Q) * rcp(P*Q);  h = (ec-1)*rcp((1+eo)(1+ec)), ec=2^min(K*c',100)
__device__ __forceinline__ f32x2 act_pair(f32x4 za, f32x4 zb, f32x2& c) {
    f32x2 ei; ei.x = exp2t(za.x); ei.y = exp2t(zb.x);
    f32x2 ef; ef.x = exp2t(za.y); ef.y = exp2t(zb.y);
    f32x2 eg; eg.x = exp2t(za.z); eg.y = exp2t(zb.z);
    f32x2 eo; eo.x = exp2t(za.w); eo.y = exp2t(zb.w);
    const f32x2 one = {1.0f, 1.0f};
    f32x2 P = (one + ei) * (one + eg);
    f32x2 Q = one + ef;
    f32x2 t;  t.x = fmaf(eg.x, Q.x, -Q.x); t.y = fmaf(eg.y, Q.y, -Q.y); // (eg-1)*Q
    f32x2 num; num.x = fmaf(c.x, P.x, t.x); num.y = fmaf(c.y, P.y, t.y);
    f32x2 den = P * Q;
    f32x2 r; r.x = rcpf(den.x); r.y = rcpf(den.y);
    c = num * r;
    f32x2 sc = c * (2.0f * LOG2E);
    sc.x = fminf(sc.x, 100.0f); sc.y = fminf(sc.y, 100.0f);   // inf*0 NaN guard
    f32x2 ec; ec.x = exp2t(sc.x); ec.y = exp2t(sc.y);
    f32x2 den2 = (one + eo) * (one + ec);
    f32x2 r2; r2.x = rcpf(den2.x); r2.y = rcpf(den2.y);
    f32x2 h; h.x = fmaf(ec.x, r2.x, -r2.x); h.y = fmaf(ec.y, r2.y, -r2.y);
    return h;
}
__device__ __forceinline__ float act_one(f32x4 za, float& c) {
    float ei = exp2t(za.x), ef = exp2t(za.y);
    float eg = exp2t(za.z), eo = exp2t(za.w);
    float P = (1.0f + ei) * (1.0f + eg);
    float Q = 1.0f + ef;
    float t = fmaf(eg, Q, -Q);
    float num = fmaf(c, P, t);
    c = num * rcpf(P * Q);
    float sc = fminf(c * (2.0f * LOG2E), 100.0f);
    float ec = exp2t(sc);
    float r2 = rcpf((1.0f + eo) * (1.0f + ec));
    return fmaf(ec, r2, -r2);
}

// ---------------------------------------------------------------------------
// Packed augmented weights, f16, PRE-SCALED by the exp2 gate factors.
// Matrix row r (0..79): m=r>>4, q=(r>>2)&3, g=r&3 -> unit u=5q+m, gate g
// (orig row ro = g*20+u). Column k follows the B-row layout above.
//   W1c [80][32] at ws[0..2559]; W2c [80][64] at ws[2560..7679].
// ---------------------------------------------------------------------------
__global__ void prep_weights(
    const float* __restrict__ Wih1, const float* __restrict__ Whh1,
    const float* __restrict__ bih1, const float* __restrict__ bhh1,
    const float* __restrict__ Wih2, const float* __restrict__ Whh2,
    const float* __restrict__ bih2, const float* __restrict__ bhh2,
    _Float16* __restrict__ ws)
{
    const int t0 = blockIdx.x * blockDim.x + threadIdx.x;
    const int stride = blockDim.x * gridDim.x;
    for (int idx = t0; idx < 80 * 32; idx += stride) {
        int r = idx >> 5, k = idx & 31;
        int m = r >> 4, q = (r >> 2) & 3, g = r & 3;
        int u = 5 * q + m, ro = g * HH + u;
        float s = (g == 2) ? 2.0f * LOG2E : -LOG2E;
        float v = 0.0f;
        if (k < 24)       { int qc = k / 6, wc = k % 6; if (wc < 5) v = Whh1[ro * HH + 5 * qc + wc]; }
        else if (k == 24)   v = Wih1[ro];
        else if (k == 25)   v = bih1[ro] + bhh1[ro];
        ws[idx] = (_Float16)(s * v);
    }
    for (int idx = t0; idx < 80 * 64; idx += stride) {
        int r = idx >> 6, k = idx & 63;
        int m = r >> 4, q = (r >> 2) & 3, g = r & 3;
        int u = 5 * q + m, ro = g * HH + u;
        float s = (g == 2) ? 2.0f * LOG2E : -LOG2E;
        float v = 0.0f;
        if (k < 24)       { int qc = k / 6, wc = k % 6; if (wc < 5) v = Wih2[ro * HH + 5 * qc + wc]; }
        else if (k == 25)   v = bih2[ro] + bhh2[ro];
        else if (k >= 26 && k < 50) {
            int cH = k - 26, qc = cH / 6, wc = cH % 6;
            if (wc < 5) v = Whh2[ro * HH + 5 * qc + wc];
        }
        ws[2560 + idx] = (_Float16)(s * v);
    }
}

// ---------------------------------------------------------------------------
// 4 waves per block, 16 elements per wave. Layer-1 A-frags (5) stationary in
// regs; layer-2 A-frags (10) in block-shared LDS, frag-major [f][lane]x16B
// (consecutive lanes -> consecutive 16B -> conflict-free ds_read_b128),
// staged once + single __syncthreads. B-rows per-wave-private (no barriers
// in the main loop). Math is bit-identical to the R4 kernel per element.
// ---------------------------------------------------------------------------
__global__ __launch_bounds__(256, 6) void lstm_mfma(
    const float* __restrict__ diag,
    const _Float16* __restrict__ wpk,
    const float* __restrict__ W1, const float* __restrict__ b1,
    const float* __restrict__ W2, const float* __restrict__ b2,
    float* __restrict__ out, int Btot)
{
    __shared__ _Float16 s_A2[10 * 64 * 8];          // 10240 B, [frag][lane] f16x8
    __shared__ _Float16 s_B[WAVES * EPW * ROWLEN];  //  9216 B, per-wave 16 rows

    const int tid  = threadIdx.x;
    const int w    = tid >> 6;
    const int lane = tid & 63;
    const int q  = lane >> 4;
    const int cc = lane & 15;
    const int e  = blockIdx.x * ELPB + w * EPW + cc;
    const int esafe = (e < Btot) ? e : (Btot - 1);
    const _Float16* W2c = wpk + 2560;

    // ---- stage layer-2 A-fragments into LDS (frag-major) ----
    for (int s = tid; s < 10 * 64; s += 256) {
        int f = s >> 6, l = s & 63;
        int ql = l >> 4, ccl = l & 15;
        int m  = (f < 5) ? f : (f - 5);
        int kb = 8 * ql + ((f < 5) ? 0 : 32);
        *(f16x8*)(s_A2 + s * 8) = *(const f16x8*)(W2c + (16 * m + ccl) * 64 + kb);
    }

    // ---- zero own wave's B-rows; set the 1.0 bias carrier once ----
    _Float16* bw = s_B + w * EPW * ROWLEN;          // wave-private slice
    if (lane < EPW) {
        uint4 zz = {0u, 0u, 0u, 0u};
        #pragma unroll
        for (int j = 0; j < 9; ++j)
            *(uint4*)((char*)bw + lane * 144 + j * 16) = zz;
        bw[lane * ROWLEN + 25] = (_Float16)1.0f;
    }

    // ---- stationary layer-1 A-fragments: A[row=16m+cc][k=8q..8q+7] ----
    f16x8 A1[5];
    {
        const int kb = q * 8;
        #pragma unroll
        for (int m = 0; m < 5; ++m)
            A1[m] = *(const f16x8*)(wpk + (16 * m + cc) * 32 + kb);
    }

    __syncthreads();   // A2 staging visible; only barrier in the kernel

    // cell state: 2 packed pairs + 1 scalar per layer
    f32x2 c1p[2], c2p[2];
    float c1s, c2s;
    c1p[0] = (f32x2){0.0f, 0.0f}; c1p[1] = (f32x2){0.0f, 0.0f};
    c2p[0] = (f32x2){0.0f, 0.0f}; c2p[1] = (f32x2){0.0f, 0.0f};
    c1s = 0.0f; c2s = 0.0f;

    const float* __restrict__ xr = diag + (long long)esafe * TSTEPS;
    float x = xr[0];
    const f32x4 zz4 = {0.0f, 0.0f, 0.0f, 0.0f};

    const _Float16* rowp = bw + cc * ROWLEN;        // this lane's B-row
    _Float16* wp1 = bw + cc * ROWLEN + 6 * q;       // h1 write base
    _Float16* wp2 = wp1 + 26;                       // h2 write base

    #pragma unroll 1
    for (int t = 0; t < TSTEPS; ++t) {
        float xn = xr[(t + 1) & (TSTEPS - 1)];      // prefetch (wraps; unused at end)

        // publish x(t) at k=24 of own row
        if (lane < EPW)
            bw[lane * ROWLEN + 24] = (_Float16)x;

        // anti-LICM: opaque zero offset so the A2 ds_reads stay in-loop
        int ah = 0;
        asm volatile("" : "+v"(ah));

        // ================= layer 1 =================
        {
            f16x8 bf = *(const f16x8*)(rowp + 8 * q);
            f32x4 z0 = mfma16(A1[0], bf, zz4);
            f32x4 z1 = mfma16(A1[1], bf, zz4);
            f32x4 z2 = mfma16(A1[2], bf, zz4);
            f32x4 z3 = mfma16(A1[3], bf, zz4);
            f32x4 z4 = mfma16(A1[4], bf, zz4);
            f32x2 h01 = act_pair(z0, z1, c1p[0]);
            *(f16x2*)(wp1) = pkrtz(h01.x, h01.y);
            f32x2 h23 = act_pair(z2, z3, c1p[1]);
            *(f16x2*)(wp1 + 2) = pkrtz(h23.x, h23.y);
            float h4 = act_one(z4, c1s);
            wp1[4] = (_Float16)h4;
        }

        // ================= layer 2 =================
        {
            f16x8 b0  = *(const f16x8*)(rowp + 8 * q);        // k 0..31
            f16x8 b1f = *(const f16x8*)(rowp + 32 + 8 * q);   // k 32..63
            f32x4 z0, z1, z2, z3, z4;
            {
                f16x8 a2a, a2b;
                a2a = *(const f16x8*)(s_A2 + (0 * 64 + lane) * 8 + ah);
                a2b = *(const f16x8*)(s_A2 + (5 * 64 + lane) * 8 + ah);
                z0 = mfma16(a2b, b1f, mfma16(a2a, b0, zz4));
                a2a = *(const f16x8*)(s_A2 + (1 * 64 + lane) * 8 + ah);
                a2b = *(const f16x8*)(s_A2 + (6 * 64 + lane) * 8 + ah);
                z1 = mfma16(a2b, b1f, mfma16(a2a, b0, zz4));
                a2a = *(const f16x8*)(s_A2 + (2 * 64 + lane) * 8 + ah);
                a2b = *(const f16x8*)(s_A2 + (7 * 64 + lane) * 8 + ah);
                z2 = mfma16(a2b, b1f, mfma16(a2a, b0, zz4));
                a2a = *(const f16x8*)(s_A2 + (3 * 64 + lane) * 8 + ah);
                a2b = *(const f16x8*)(s_A2 + (8 * 64 + lane) * 8 + ah);
                z3 = mfma16(a2b, b1f, mfma16(a2a, b0, zz4));
                a2a = *(const f16x8*)(s_A2 + (4 * 64 + lane) * 8 + ah);
                a2b = *(const f16x8*)(s_A2 + (9 * 64 + lane) * 8 + ah);
                z4 = mfma16(a2b, b1f, mfma16(a2a, b0, zz4));
            }
            f32x2 h01 = act_pair(z0, z1, c2p[0]);
            *(f16x2*)(wp2) = pkrtz(h01.x, h01.y);
            f32x2 h23 = act_pair(z2, z3, c2p[1]);
            *(f16x2*)(wp2 + 2) = pkrtz(h23.x, h23.y);
            float h4 = act_one(z4, c2s);
            wp2[4] = (_Float16)h4;
        }

        x = xn;
    }

    // ---- head: relu(relu(h2 @ W1^T + b1) @ W2^T + b2), fp32, lanes 0..15 ----
    if (lane < EPW && e < Btot) {
        const _Float16* hp = bw + lane * ROWLEN + 26;
        float hv[HH];
        #pragma unroll
        for (int qq = 0; qq < 4; ++qq)
            #pragma unroll
            for (int ww = 0; ww < 5; ++ww)
                hv[5 * qq + ww] = (float)hp[6 * qq + ww];     // un-permute 6-stride

        float y2 = b2[0];
        #pragma unroll 1
        for (int jj = 0; jj < FF; ++jj) {
            float a = b1[jj];
            const float* __restrict__ wj = W1 + jj * HH;
            #pragma unroll
            for (int k = 0; k < HH; ++k)
                a = fmaf(hv[k], wj[k], a);
            a = fmaxf(a, 0.0f);
            y2 = fmaf(a, W2[jj], y2);
        }
        out[e] = fmaxf(y2, 0.0f);
    }
}

extern "C" void kernel_launch(void* const* d_in, const int* in_sizes, int n_in,
                              void* d_out, int out_size, void* d_ws, size_t ws_size,
                              hipStream_t stream)
{
    (void)n_in; (void)ws_size; (void)out_size;
    const float* diag = (const float*)d_in[0];
    const float* Wih1 = (const float*)d_in[1];
    const float* Whh1 = (const float*)d_in[2];
    const float* bih1 = (const float*)d_in[3];
    const float* bhh1 = (const float*)d_in[4];
    const float* Wih2 = (const float*)d_in[5];
    const float* Whh2 = (const float*)d_in[6];
    const float* bih2 = (const float*)d_in[7];
    const float* bhh2 = (const float*)d_in[8];
    const float* W1   = (const float*)d_in[9];
    const float* b1   = (const float*)d_in[10];
    const float* W2   = (const float*)d_in[11];
    const float* b2   = (const float*)d_in[12];

    const int Btot = in_sizes[0] / TSTEPS;   // 131072
    _Float16* wpk = (_Float16*)d_ws;

    prep_weights<<<8, 256, 0, stream>>>(Wih1, Whh1, bih1, bhh1,
                                        Wih2, Whh2, bih2, bhh2, wpk);

    lstm_mfma<<<(Btot + ELPB - 1) / ELPB, 256, 0, stream>>>(
        diag, wpk, W1, b1, W2, b2, (float*)d_out, Btot);
}

// Round 8
// 1231.012 us; speedup vs baseline: 1.4410x; 1.0246x over previous
//
#include <hip/hip_runtime.h>

#define HH 20
#define TSTEPS 256
#define FF 64
#define EPW 16             // batch elements per wave
#define WAVES 4            // waves per block
#define ELPB (EPW * WAVES) // 64 elements per block
#define ROWLEN 72          // f16 per LDS B-row; 144 B stride (16B-aligned)
#define LOG2E 1.44269504088896f
// B-row layout (f16 idx): [0..23] h1, 6-stride (lane q writes 6q..6q+4, 6q+5 pad)
//   [24]=x, [25]=1.0 (bias carrier, written once), [26..49] h2 (6-stride), [50..71] zero

typedef __attribute__((ext_vector_type(8))) _Float16 f16x8;
typedef __attribute__((ext_vector_type(2))) _Float16 f16x2;
typedef __attribute__((ext_vector_type(4))) float    f32x4;
typedef __attribute__((ext_vector_type(2))) float    f32x2;

__device__ __forceinline__ f16x2 pkrtz(float a, float b) {
    return __builtin_bit_cast(f16x2, __builtin_amdgcn_cvt_pkrtz(a, b));
}
__device__ __forceinline__ f32x4 mfma16(f16x8 a, f16x8 b, f32x4 c) {
    return __builtin_amdgcn_mfma_f32_16x16x32_f16(a, b, c, 0, 0, 0);
}
__device__ __forceinline__ float rcpf(float x) { return __builtin_amdgcn_rcpf(x); }
__device__ __forceinline__ float exp2t(float x) {          // v_exp_f32 (2^x native)
#if __has_builtin(__builtin_amdgcn_exp2f)
    return __builtin_amdgcn_exp2f(x);
#else
    return __expf(x * 0.6931471805599453f);
#endif
}

// Gate quads arrive pre-scaled: si=-log2e*zi, sf=-log2e*zf, sg=2log2e*zg, so=-log2e*zo.
// Pair-merged-rcp form: for the 2 units of a pair, rcp(d1),rcp(d2) ->
//   rr=rcp(d1*d2); r1=rr*d2; r2=rr*d1   (saves 1 trans op per merge, 4 merges/lane/layer)
// Overflow audit (worst case): den1 <= 2^53.5 per unit -> pair product <= 2^107 < f32max;
// sc clamp at 24 (tanh(24/2.88)=1-2e-8, invisible at f16) bounds den2 <= 2^37.4 -> pair 2^75.
// All dens >= 1, no underflow.
__device__ __forceinline__ f32x2 act_pair(f32x4 za, f32x4 zb, f32x2& c) {
    f32x2 ei; ei.x = exp2t(za.x); ei.y = exp2t(zb.x);
    f32x2 ef; ef.x = exp2t(za.y); ef.y = exp2t(zb.y);
    f32x2 eg; eg.x = exp2t(za.z); eg.y = exp2t(zb.z);
    f32x2 eo; eo.x = exp2t(za.w); eo.y = exp2t(zb.w);
    const f32x2 one = {1.0f, 1.0f};
    f32x2 ug = one + eg;
    f32x2 P;  P.x = fmaf(ei.x, ug.x, ug.x); P.y = fmaf(ei.y, ug.y, ug.y);  // (1+ei)(1+eg)
    f32x2 Q = one + ef;
    f32x2 t;  t.x = fmaf(eg.x, Q.x, -Q.x); t.y = fmaf(eg.y, Q.y, -Q.y);   // (eg-1)*Q
    f32x2 num; num.x = fmaf(c.x, P.x, t.x); num.y = fmaf(c.y, P.y, t.y);
    f32x2 den = P * Q;
    float rr = rcpf(den.x * den.y);                 // merged rcp #1
    f32x2 r; r.x = rr * den.y; r.y = rr * den.x;
    c = num * r;
    f32x2 sc = c * (2.0f * LOG2E);
    sc.x = fminf(sc.x, 24.0f); sc.y = fminf(sc.y, 24.0f);   // saturation + overflow guard
    f32x2 ec; ec.x = exp2t(sc.x); ec.y = exp2t(sc.y);
    f32x2 uc = one + ec;
    f32x2 den2; den2.x = fmaf(eo.x, uc.x, uc.x); den2.y = fmaf(eo.y, uc.y, uc.y);
    float rr2 = rcpf(den2.x * den2.y);              // merged rcp #2
    f32x2 r2; r2.x = rr2 * den2.y; r2.y = rr2 * den2.x;
    f32x2 h; h.x = fmaf(ec.x, r2.x, -r2.x); h.y = fmaf(ec.y, r2.y, -r2.y);
    return h;
}
__device__ __forceinline__ float act_one(f32x4 za, float& c) {
    float ei = exp2t(za.x), ef = exp2t(za.y);
    float eg = exp2t(za.z), eo = exp2t(za.w);
    float ug = 1.0f + eg;
    float P = fmaf(ei, ug, ug);
    float Q = 1.0f + ef;
    float t = fmaf(eg, Q, -Q);
    float num = fmaf(c, P, t);
    c = num * rcpf(P * Q);
    float sc = fminf(c * (2.0f * LOG2E), 24.0f);
    float ec = exp2t(sc);
    float uc = 1.0f + ec;
    float den2 = fmaf(eo, uc, uc);
    float r2 = rcpf(den2);
    return fmaf(ec, r2, -r2);
}

// ---------------------------------------------------------------------------
// Packed augmented weights, f16, PRE-SCALED by the exp2 gate factors.
// Matrix row r (0..79): m=r>>4, q=(r>>2)&3, g=r&3 -> unit u=5q+m, gate g
// (orig row ro = g*20+u). Column k follows the B-row layout above.
//   W1c [80][32] at ws[0..2559]; W2c [80][64] at ws[2560..7679].
// ---------------------------------------------------------------------------
__global__ void prep_weights(
    const float* __restrict__ Wih1, const float* __restrict__ Whh1,
    const float* __restrict__ bih1, const float* __restrict__ bhh1,
    const float* __restrict__ Wih2, const float* __restrict__ Whh2,
    const float* __restrict__ bih2, const float* __restrict__ bhh2,
    _Float16* __restrict__ ws)
{
    const int t0 = blockIdx.x * blockDim.x + threadIdx.x;
    const int stride = blockDim.x * gridDim.x;
    for (int idx = t0; idx < 80 * 32; idx += stride) {
        int r = idx >> 5, k = idx & 31;
        int m = r >> 4, q = (r >> 2) & 3, g = r & 3;
        int u = 5 * q + m, ro = g * HH + u;
        float s = (g == 2) ? 2.0f * LOG2E : -LOG2E;
        float v = 0.0f;
        if (k < 24)       { int qc = k / 6, wc = k % 6; if (wc < 5) v = Whh1[ro * HH + 5 * qc + wc]; }
        else if (k == 24)   v = Wih1[ro];
        else if (k == 25)   v = bih1[ro] + bhh1[ro];
        ws[idx] = (_Float16)(s * v);
    }
    for (int idx = t0; idx < 80 * 64; idx += stride) {
        int r = idx >> 6, k = idx & 63;
        int m = r >> 4, q = (r >> 2) & 3, g = r & 3;
        int u = 5 * q + m, ro = g * HH + u;
        float s = (g == 2) ? 2.0f * LOG2E : -LOG2E;
        float v = 0.0f;
        if (k < 24)       { int qc = k / 6, wc = k % 6; if (wc < 5) v = Wih2[ro * HH + 5 * qc + wc]; }
        else if (k == 25)   v = bih2[ro] + bhh2[ro];
        else if (k >= 26 && k < 50) {
            int cH = k - 26, qc = cH / 6, wc = cH % 6;
            if (wc < 5) v = Whh2[ro * HH + 5 * qc + wc];
        }
        ws[2560 + idx] = (_Float16)(s * v);
    }
}

// ---------------------------------------------------------------------------
// 4 waves per block, 16 elements per wave. Layer-1 A-frags (5) stationary in
// regs; layer-2 A-frags (10) in block-shared LDS, frag-major [f][lane]x16B
// (conflict-free ds_read_b128), staged once + single __syncthreads.
// B-rows per-wave-private (no barriers in the main loop).
// ---------------------------------------------------------------------------
__global__ __launch_bounds__(256, 6) void lstm_mfma(
    const float* __restrict__ diag,
    const _Float16* __restrict__ wpk,
    const float* __restrict__ W1, const float* __restrict__ b1,
    const float* __restrict__ W2, const float* __restrict__ b2,
    float* __restrict__ out, int Btot)
{
    __shared__ _Float16 s_A2[10 * 64 * 8];          // 10240 B, [frag][lane] f16x8
    __shared__ _Float16 s_B[WAVES * EPW * ROWLEN];  //  9216 B, per-wave 16 rows

    const int tid  = threadIdx.x;
    const int w    = tid >> 6;
    const int lane = tid & 63;
    const int q  = lane >> 4;
    const int cc = lane & 15;
    const int e  = blockIdx.x * ELPB + w * EPW + cc;
    const int esafe = (e < Btot) ? e : (Btot - 1);
    const _Float16* W2c = wpk + 2560;

    // ---- stage layer-2 A-fragments into LDS (frag-major) ----
    for (int s = tid; s < 10 * 64; s += 256) {
        int f = s >> 6, l = s & 63;
        int ql = l >> 4, ccl = l & 15;
        int m  = (f < 5) ? f : (f - 5);
        int kb = 8 * ql + ((f < 5) ? 0 : 32);
        *(f16x8*)(s_A2 + s * 8) = *(const f16x8*)(W2c + (16 * m + ccl) * 64 + kb);
    }

    // ---- zero own wave's B-rows; set the 1.0 bias carrier once ----
    _Float16* bw = s_B + w * EPW * ROWLEN;          // wave-private slice
    if (lane < EPW) {
        uint4 zz = {0u, 0u, 0u, 0u};
        #pragma unroll
        for (int j = 0; j < 9; ++j)
            *(uint4*)((char*)bw + lane * 144 + j * 16) = zz;
        bw[lane * ROWLEN + 25] = (_Float16)1.0f;
    }

    // ---- stationary layer-1 A-fragments: A[row=16m+cc][k=8q..8q+7] ----
    f16x8 A1[5];
    {
        const int kb = q * 8;
        #pragma unroll
        for (int m = 0; m < 5; ++m)
            A1[m] = *(const f16x8*)(wpk + (16 * m + cc) * 32 + kb);
    }

    __syncthreads();   // A2 staging visible; only barrier in the kernel

    // cell state: 2 packed pairs + 1 scalar per layer
    f32x2 c1p[2], c2p[2];
    float c1s, c2s;
    c1p[0] = (f32x2){0.0f, 0.0f}; c1p[1] = (f32x2){0.0f, 0.0f};
    c2p[0] = (f32x2){0.0f, 0.0f}; c2p[1] = (f32x2){0.0f, 0.0f};
    c1s = 0.0f; c2s = 0.0f;

    const float* __restrict__ xr = diag + (long long)esafe * TSTEPS;
    float x = xr[0];
    const f32x4 zz4 = {0.0f, 0.0f, 0.0f, 0.0f};

    const _Float16* rowp = bw + cc * ROWLEN;        // this lane's B-row
    _Float16* wp1 = bw + cc * ROWLEN + 6 * q;       // h1 write base
    _Float16* wp2 = wp1 + 26;                       // h2 write base

    #pragma unroll 1
    for (int t = 0; t < TSTEPS; ++t) {
        float xn = xr[(t + 1) & (TSTEPS - 1)];      // prefetch (wraps; unused at end)

        // publish x(t) at k=24 of own row
        if (lane < EPW)
            bw[lane * ROWLEN + 24] = (_Float16)x;

        // anti-LICM: opaque zero offset so the A2 ds_reads stay in-loop
        int ah = 0;
        asm volatile("" : "+v"(ah));

        // ================= layer 1 =================
        {
            f16x8 bf = *(const f16x8*)(rowp + 8 * q);
            f32x4 z0 = mfma16(A1[0], bf, zz4);
            f32x4 z1 = mfma16(A1[1], bf, zz4);
            f32x4 z2 = mfma16(A1[2], bf, zz4);
            f32x4 z3 = mfma16(A1[3], bf, zz4);
            f32x4 z4 = mfma16(A1[4], bf, zz4);
            f32x2 h01 = act_pair(z0, z1, c1p[0]);
            *(f16x2*)(wp1) = pkrtz(h01.x, h01.y);
            f32x2 h23 = act_pair(z2, z3, c1p[1]);
            *(f16x2*)(wp1 + 2) = pkrtz(h23.x, h23.y);
            float h4 = act_one(z4, c1s);
            wp1[4] = (_Float16)h4;
        }

        // ================= layer 2 =================
        {
            f16x8 b0  = *(const f16x8*)(rowp + 8 * q);        // k 0..31
            f16x8 b1f = *(const f16x8*)(rowp + 32 + 8 * q);   // k 32..63
            f32x4 z0, z1, z2, z3, z4;
            {
                f16x8 a2a, a2b;
                a2a = *(const f16x8*)(s_A2 + (0 * 64 + lane) * 8 + ah);
                a2b = *(const f16x8*)(s_A2 + (5 * 64 + lane) * 8 + ah);
                z0 = mfma16(a2b, b1f, mfma16(a2a, b0, zz4));
                a2a = *(const f16x8*)(s_A2 + (1 * 64 + lane) * 8 + ah);
                a2b = *(const f16x8*)(s_A2 + (6 * 64 + lane) * 8 + ah);
                z1 = mfma16(a2b, b1f, mfma16(a2a, b0, zz4));
                a2a = *(const f16x8*)(s_A2 + (2 * 64 + lane) * 8 + ah);
                a2b = *(const f16x8*)(s_A2 + (7 * 64 + lane) * 8 + ah);
                z2 = mfma16(a2b, b1f, mfma16(a2a, b0, zz4));
                a2a = *(const f16x8*)(s_A2 + (3 * 64 + lane) * 8 + ah);
                a2b = *(const f16x8*)(s_A2 + (8 * 64 + lane) * 8 + ah);
                z3 = mfma16(a2b, b1f, mfma16(a2a, b0, zz4));
                a2a = *(const f16x8*)(s_A2 + (4 * 64 + lane) * 8 + ah);
                a2b = *(const f16x8*)(s_A2 + (9 * 64 + lane) * 8 + ah);
                z4 = mfma16(a2b, b1f, mfma16(a2a, b0, zz4));
            }
            f32x2 h01 = act_pair(z0, z1, c2p[0]);
            *(f16x2*)(wp2) = pkrtz(h01.x, h01.y);
            f32x2 h23 = act_pair(z2, z3, c2p[1]);
            *(f16x2*)(wp2 + 2) = pkrtz(h23.x, h23.y);
            float h4 = act_one(z4, c2s);
            wp2[4] = (_Float16)h4;
        }

        x = xn;
    }

    // ---- head: relu(relu(h2 @ W1^T + b1) @ W2^T + b2), fp32, lanes 0..15 ----
    if (lane < EPW && e < Btot) {
        const _Float16* hp = bw + lane * ROWLEN + 26;
        float hv[HH];
        #pragma unroll
        for (int qq = 0; qq < 4; ++qq)
            #pragma unroll
            for (int ww = 0; ww < 5; ++ww)
                hv[5 * qq + ww] = (float)hp[6 * qq + ww];     // un-permute 6-stride

        float y2 = b2[0];
        #pragma unroll 1
        for (int jj = 0; jj < FF; ++jj) {
            float a = b1[jj];
            const float* __restrict__ wj = W1 + jj * HH;
            #pragma unroll
            for (int k = 0; k < HH; ++k)
                a = fmaf(hv[k], wj[k], a);
            a = fmaxf(a, 0.0f);
            y2 = fmaf(a, W2[jj], y2);
        }
        out[e] = fmaxf(y2, 0.0f);
    }
}

extern "C" void kernel_launch(void* const* d_in, const int* in_sizes, int n_in,
                              void* d_out, int out_size, void* d_ws, size_t ws_size,
                              hipStream_t stream)
{
    (void)n_in; (void)ws_size; (void)out_size;
    const float* diag = (const float*)d_in[0];
    const float* Wih1 = (const float*)d_in[1];
    const float* Whh1 = (const float*)d_in[2];
    const float* bih1 = (const float*)d_in[3];
    const float* bhh1 = (const float*)d_in[4];
    const float* Wih2 = (const float*)d_in[5];
    const float* Whh2 = (const float*)d_in[6];
    const float* bih2 = (const float*)d_in[7];
    const float* bhh2 = (const float*)d_in[8];
    const float* W1   = (const float*)d_in[9];
    const float* b1   = (const float*)d_in[10];
    const float* W2   = (const float*)d_in[11];
    const float* b2   = (const float*)d_in[12];

    const int Btot = in_sizes[0] / TSTEPS;   // 131072
    _Float16* wpk = (_Float16*)d_ws;

    prep_weights<<<8, 256, 0, stream>>>(Wih1, Whh1, bih1, bhh1,
                                        Wih2, Whh2, bih2, bhh2, wpk);

    lstm_mfma<<<(Btot + ELPB - 1) / ELPB, 256, 0, stream>>>(
        diag, wpk, W1, b1, W2, b2, (float*)d_out, Btot);
}